// Round 5
// baseline (540.175 us; speedup 1.0000x reference)
//
#include <hip/hip_runtime.h>
#include <stdint.h>

// ---------------------------------------------------------------------------
// 3-layer GraphSAGE (mean aggregation) on MI355X — split-bf16 MFMA edition.
//
// All feature matrices live as bf16 hi/lo PLANE PAIRS ([N][128] ushort each):
//   v_f32 ~= bf2f(hi) + bf2f(lo)   (error ~2^-17 rel, << fp32 reorder noise)
// CSR build (hist->scan->fill), then per layer:
//   k_aggP : gather-mean over hi/lo planes, fp32 accum, emits split agg planes
//   k_gemm : out = [agg|h] @ [Wl;Wr] + b via mfma_f32_32x32x16_bf16,
//            3-MFMA split product (ah*bh + ah*bl + al*bh), fp32 accumulators.
//            Tile 64 nodes x 128 cols, K=256 in 4 chunks of 64.
// Buffer ping-pong: x planes (ws) -> h1 planes (d_out) -> h2 planes (ws) ->
// fp32 out (d_out). In-place-safe: each gemm block only reads/writes its own
// 64 rows; layer-3 reads h2 from ws while writing fp32 to d_out (no alias).
// ---------------------------------------------------------------------------

using bf16x8 = __attribute__((ext_vector_type(8))) __bf16;
using f32x16 = __attribute__((ext_vector_type(16))) float;

__device__ inline unsigned short f2bf(float v) {           // RNE f32->bf16
    uint32_t u = __float_as_uint(v);
    uint32_t r = u + 0x7FFF + ((u >> 16) & 1);
    return (unsigned short)(r >> 16);
}
__device__ inline float bf2f(unsigned short h) {
    return __uint_as_float(((uint32_t)h) << 16);
}

// ---------------- CSR build ----------------
__global__ void k_hist(const int* __restrict__ dst, int* __restrict__ deg, int E)
{
    int i = blockIdx.x * blockDim.x + threadIdx.x;
    int stride = gridDim.x * blockDim.x;
    for (; i < E; i += stride) atomicAdd(&deg[dst[i]], 1);
}

__global__ __launch_bounds__(1024) void k_scan(const int* __restrict__ deg,
                                               int* __restrict__ rp,
                                               int* __restrict__ cur, int n)
{
    __shared__ int wsum[16];
    __shared__ int carry_s;
    int tid = threadIdx.x, lane = tid & 63, w = tid >> 6;
    if (tid == 0) carry_s = 0;
    __syncthreads();
    for (int base = 0; base < n; base += 4096) {
        int i = base + tid * 4;
        int4 v = make_int4(0, 0, 0, 0);
        if (i + 3 < n) v = *(const int4*)(deg + i);
        else {
            if (i     < n) v.x = deg[i];
            if (i + 1 < n) v.y = deg[i + 1];
            if (i + 2 < n) v.z = deg[i + 2];
            if (i + 3 < n) v.w = deg[i + 3];
        }
        int t = v.x + v.y + v.z + v.w;
        int s = t;
        #pragma unroll
        for (int d = 1; d < 64; d <<= 1) { int u = __shfl_up(s, d); if (lane >= d) s += u; }
        if (lane == 63) wsum[w] = s;
        __syncthreads();
        if (w == 0 && lane < 16) {
            int u = wsum[lane];
            #pragma unroll
            for (int d = 1; d < 16; d <<= 1) { int y = __shfl_up(u, d); if (lane >= d) u += y; }
            wsum[lane] = u;
        }
        __syncthreads();
        int carry = carry_s;
        int off = carry + (w ? wsum[w - 1] : 0) + (s - t);
        int r0 = off, r1 = r0 + v.x, r2 = r1 + v.y, r3 = r2 + v.z;
        if (i + 3 < n) {
            *(int4*)(rp + i)  = make_int4(r0, r1, r2, r3);
            *(int4*)(cur + i) = make_int4(r0, r1, r2, r3);
        } else {
            if (i     < n) { rp[i]     = r0; cur[i]     = r0; }
            if (i + 1 < n) { rp[i + 1] = r1; cur[i + 1] = r1; }
            if (i + 2 < n) { rp[i + 2] = r2; cur[i + 2] = r2; }
            if (i + 3 < n) { rp[i + 3] = r3; cur[i + 3] = r3; }
        }
        __syncthreads();
        if (tid == 1023) carry_s = carry + wsum[15];
    }
    __syncthreads();
    if (tid == 0) rp[n] = carry_s;
}

__global__ void k_fill(const int* __restrict__ src, const int* __restrict__ dst,
                       int* __restrict__ cur, int* __restrict__ col, int E)
{
    int i = blockIdx.x * blockDim.x + threadIdx.x;
    int stride = gridDim.x * blockDim.x;
    for (; i < E; i += stride) {
        int p = atomicAdd(&cur[dst[i]], 1);
        col[p] = src[i];
    }
}

// ---------------- split helpers ----------------
// x fp32 -> hi/lo bf16 planes. Grid-stride over float4.
__global__ __launch_bounds__(256) void k_splitX(const float* __restrict__ x,
                                                unsigned short* __restrict__ ph,
                                                unsigned short* __restrict__ pl,
                                                int total4)
{
    int i = blockIdx.x * blockDim.x + threadIdx.x;
    int stride = gridDim.x * blockDim.x;
    for (; i < total4; i += stride) {
        float4 v = ((const float4*)x)[i];
        ushort4 h, l;
        float f;
        h.x = f2bf(v.x); f = bf2f(h.x); l.x = f2bf(v.x - f);
        h.y = f2bf(v.y); f = bf2f(h.y); l.y = f2bf(v.y - f);
        h.z = f2bf(v.z); f = bf2f(h.z); l.z = f2bf(v.z - f);
        h.w = f2bf(v.w); f = bf2f(h.w); l.w = f2bf(v.w - f);
        ((ushort4*)ph)[i] = h;
        ((ushort4*)pl)[i] = l;
    }
}

// W -> packed, pre-swizzled LDS image. Virtual W = [Wl;Wr] (256x128).
// Image per chunk ch (k0=(ch&1)*64, mat = ch<2?Wl:Wr):
//   [hi 16KB][lo 16KB]; within a plane, row c (128B): slot s'=(kk>>3)^(c&7),
//   ushort idx = c*64 + s'*8 + (kk&7). 4 chunks = 128KB per layer.
__global__ __launch_bounds__(256) void k_splitW(const float* __restrict__ Wl,
                                                const float* __restrict__ Wr,
                                                unsigned short* __restrict__ img)
{
    int idx = blockIdx.x * 256 + threadIdx.x;       // 32768 total
    int ch = idx >> 13;
    int rem = idx & 8191;
    int kk = rem >> 7;
    int c  = rem & 127;
    int kg = (ch & 1) * 64 + kk;
    float v = (ch < 2 ? Wl : Wr)[kg * 128 + c];
    unsigned short h = f2bf(v);
    unsigned short l = f2bf(v - bf2f(h));
    int sl = (kk >> 3) ^ (c & 7);
    int o  = ch * 16384 + c * 64 + sl * 8 + (kk & 7);
    img[o]        = h;
    img[o + 8192] = l;
}

// ---------------- aggregation over hi/lo planes ----------------
// One wave per node; lane l owns dims 2l,2l+1 (one uint per plane per row).
__global__ __launch_bounds__(256) void k_aggP(const unsigned short* __restrict__ hh,
                                              const unsigned short* __restrict__ hl,
                                              const int* __restrict__ rp,
                                              const int* __restrict__ col,
                                              unsigned short* __restrict__ ah,
                                              unsigned short* __restrict__ al,
                                              int nNodes)
{
    int gw   = (blockIdx.x * blockDim.x + threadIdx.x) >> 6;
    int lane = threadIdx.x & 63;
    int nw   = (gridDim.x * blockDim.x) >> 6;
    for (int n = gw; n < nNodes; n += nw) {
        int s = rp[n], e = rp[n + 1];
        float a0 = 0.f, a1 = 0.f, b0 = 0.f, b1 = 0.f;
        int i = s;
        for (; i + 2 <= e; i += 2) {
            int c0 = col[i], c1 = col[i + 1];
            uint32_t h0 = *(const uint32_t*)(hh + (size_t)c0 * 128 + lane * 2);
            uint32_t l0 = *(const uint32_t*)(hl + (size_t)c0 * 128 + lane * 2);
            uint32_t h1 = *(const uint32_t*)(hh + (size_t)c1 * 128 + lane * 2);
            uint32_t l1 = *(const uint32_t*)(hl + (size_t)c1 * 128 + lane * 2);
            a0 += __uint_as_float(h0 << 16) + __uint_as_float(l0 << 16);
            a1 += __uint_as_float(h0 & 0xffff0000u) + __uint_as_float(l0 & 0xffff0000u);
            b0 += __uint_as_float(h1 << 16) + __uint_as_float(l1 << 16);
            b1 += __uint_as_float(h1 & 0xffff0000u) + __uint_as_float(l1 & 0xffff0000u);
        }
        if (i < e) {
            int c0 = col[i];
            uint32_t h0 = *(const uint32_t*)(hh + (size_t)c0 * 128 + lane * 2);
            uint32_t l0 = *(const uint32_t*)(hl + (size_t)c0 * 128 + lane * 2);
            a0 += __uint_as_float(h0 << 16) + __uint_as_float(l0 << 16);
            a1 += __uint_as_float(h0 & 0xffff0000u) + __uint_as_float(l0 & 0xffff0000u);
        }
        float inv = (e > s) ? (1.f / (float)(e - s)) : 0.f;
        float m0 = (a0 + b0) * inv, m1 = (a1 + b1) * inv;
        unsigned short h0s = f2bf(m0), h1s = f2bf(m1);
        unsigned short l0s = f2bf(m0 - bf2f(h0s)), l1s = f2bf(m1 - bf2f(h1s));
        *(uint32_t*)(ah + (size_t)n * 128 + lane * 2) = (uint32_t)h0s | ((uint32_t)h1s << 16);
        *(uint32_t*)(al + (size_t)n * 128 + lane * 2) = (uint32_t)l0s | ((uint32_t)l1s << 16);
    }
}

// ---------------- split-bf16 MFMA GEMM ----------------
// Block: 256 thr (4 waves, 2x2), tile M=64 x N=128, K=256 in 4 chunks of 64.
// Wave (wm,wn): one 32-row m-tile, two 32-col n-tiles. 32x32x16 bf16 MFMA.
// Frag maps (A row / B col = lane&31, k = (lane>>5)*8+j): A/B share the same
// k-map so any consistent permutation is correctness-neutral. C/D layout
// (verified m74/m101): col=lane&31, row=(reg&3)+8*(reg>>2)+4*(lane>>5).
// LDS 48KB: Ah[64x64] Al Bh[128x64] Bl bf16, 128B rows, slot^=(row&7) swizzle
// -> frag b128 reads sit at the 4-lanes/quad structural floor (no conflicts).
__global__ __launch_bounds__(256) void k_gemm(const unsigned short* __restrict__ aggH,
                                              const unsigned short* __restrict__ aggL,
                                              const unsigned short* hH,
                                              const unsigned short* hL,
                                              const unsigned short* __restrict__ wimg,
                                              const float* __restrict__ bias,
                                              float* outF,
                                              unsigned short* oH,
                                              unsigned short* oL,
                                              int relu, int nNodes)
{
    __shared__ unsigned short lds[24576];     // 48KB
    constexpr int AH = 0, AL = 4096, BH = 8192, BL = 16384;   // ushort offsets

    const int tid  = threadIdx.x;
    const int wave = tid >> 6, l = tid & 63;
    const int lh   = l >> 5, l31 = l & 31;
    const int wm = wave >> 1, wn = wave & 1;
    const int m0w = wm * 32, n0w = wn * 64;
    const int node0 = blockIdx.x * 64;

    // staging geometry: thread -> (row r_s, slot s'), source slot = s'^(r_s&7)
    const int r_s   = tid >> 3;          // 0..31
    const int sp    = tid & 7;           // LDS slot
    const int ssrc  = sp ^ (r_s & 7);    // source slot
    const int offA  = r_s * 64 + sp * 8; // ushort off within a 32-row A half

    f32x16 acc0, acc1;
    #pragma unroll
    for (int i = 0; i < 16; ++i) { acc0[i] = 0.f; acc1[i] = 0.f; }

    uint4 rA[4];   // Ah s0, Ah s1, Al s0, Al s1
    uint4 rB[8];   // Bh s0..3, Bl s0..3

    auto load12 = [&](int ch) {
        const unsigned short* sH = (ch < 2) ? aggH : hH;
        const unsigned short* sL = (ch < 2) ? aggL : hL;
        const int k0 = (ch & 1) * 64;
        size_t r0 = (size_t)min(node0 + r_s,      nNodes - 1) * 128 + k0 + ssrc * 8;
        size_t r1 = (size_t)min(node0 + 32 + r_s, nNodes - 1) * 128 + k0 + ssrc * 8;
        rA[0] = *(const uint4*)(sH + r0);
        rA[1] = *(const uint4*)(sH + r1);
        rA[2] = *(const uint4*)(sL + r0);
        rA[3] = *(const uint4*)(sL + r1);
        const unsigned short* w = wimg + ch * 16384;
        #pragma unroll
        for (int s = 0; s < 4; ++s) {
            rB[s]     = *(const uint4*)(w + s * 2048 + tid * 8);
            rB[4 + s] = *(const uint4*)(w + 8192 + s * 2048 + tid * 8);
        }
    };
    auto write12 = [&]() {
        *(uint4*)&lds[AH + offA]        = rA[0];
        *(uint4*)&lds[AH + 2048 + offA] = rA[1];
        *(uint4*)&lds[AL + offA]        = rA[2];
        *(uint4*)&lds[AL + 2048 + offA] = rA[3];
        #pragma unroll
        for (int s = 0; s < 4; ++s) {
            *(uint4*)&lds[BH + s * 2048 + tid * 8] = rB[s];
            *(uint4*)&lds[BL + s * 2048 + tid * 8] = rB[4 + s];
        }
    };

    load12(0);
    #pragma unroll 1
    for (int ch = 0; ch < 4; ++ch) {
        __syncthreads();                  // prior chunk's LDS reads done
        write12();
        __syncthreads();                  // LDS ready
        if (ch < 3) load12(ch + 1);       // prefetch next chunk (regs only)

        const int rowA = m0w + l31;
        const int rowB0 = n0w + l31, rowB1 = rowB0 + 32;
        #pragma unroll
        for (int ks = 0; ks < 4; ++ks) {
            const int sg = ks * 2 + lh;
            bf16x8 a_h = *(const bf16x8*)&lds[AH + rowA * 64 + ((sg ^ (rowA & 7)) << 3)];
            bf16x8 a_l = *(const bf16x8*)&lds[AL + rowA * 64 + ((sg ^ (rowA & 7)) << 3)];
            bf16x8 b_h0 = *(const bf16x8*)&lds[BH + rowB0 * 64 + ((sg ^ (rowB0 & 7)) << 3)];
            bf16x8 b_l0 = *(const bf16x8*)&lds[BL + rowB0 * 64 + ((sg ^ (rowB0 & 7)) << 3)];
            bf16x8 b_h1 = *(const bf16x8*)&lds[BH + rowB1 * 64 + ((sg ^ (rowB1 & 7)) << 3)];
            bf16x8 b_l1 = *(const bf16x8*)&lds[BL + rowB1 * 64 + ((sg ^ (rowB1 & 7)) << 3)];
            acc0 = __builtin_amdgcn_mfma_f32_32x32x16_bf16(a_h, b_h0, acc0, 0, 0, 0);
            acc1 = __builtin_amdgcn_mfma_f32_32x32x16_bf16(a_h, b_h1, acc1, 0, 0, 0);
            acc0 = __builtin_amdgcn_mfma_f32_32x32x16_bf16(a_h, b_l0, acc0, 0, 0, 0);
            acc1 = __builtin_amdgcn_mfma_f32_32x32x16_bf16(a_h, b_l1, acc1, 0, 0, 0);
            acc0 = __builtin_amdgcn_mfma_f32_32x32x16_bf16(a_l, b_h0, acc0, 0, 0, 0);
            acc1 = __builtin_amdgcn_mfma_f32_32x32x16_bf16(a_l, b_h1, acc1, 0, 0, 0);
        }
    }

    // epilogue
    const float bv0 = bias[n0w + l31];
    const float bv1 = bias[n0w + 32 + l31];
    #pragma unroll
    for (int reg = 0; reg < 16; ++reg) {
        int row = (reg & 3) + 8 * (reg >> 2) + 4 * lh;
        int gn  = node0 + m0w + row;
        if (gn < nNodes) {
            float v0 = acc0[reg] + bv0;
            float v1 = acc1[reg] + bv1;
            if (relu) { v0 = fmaxf(v0, 0.f); v1 = fmaxf(v1, 0.f); }
            if (outF) {
                outF[(size_t)gn * 128 + n0w + l31]      = v0;
                outF[(size_t)gn * 128 + n0w + 32 + l31] = v1;
            } else {
                unsigned short h0 = f2bf(v0), h1 = f2bf(v1);
                oH[(size_t)gn * 128 + n0w + l31]      = h0;
                oH[(size_t)gn * 128 + n0w + 32 + l31] = h1;
                oL[(size_t)gn * 128 + n0w + l31]      = f2bf(v0 - bf2f(h0));
                oL[(size_t)gn * 128 + n0w + 32 + l31] = f2bf(v1 - bf2f(h1));
            }
        }
    }
}

extern "C" void kernel_launch(void* const* d_in, const int* in_sizes, int n_in,
                              void* d_out, int out_size, void* d_ws, size_t ws_size,
                              hipStream_t stream)
{
    const float* x   = (const float*)d_in[0];
    const int*   ei  = (const int*)d_in[1];
    const float* Wl1 = (const float*)d_in[2];
    const float* b1  = (const float*)d_in[3];
    const float* Wr1 = (const float*)d_in[4];
    const float* Wl2 = (const float*)d_in[5];
    const float* b2  = (const float*)d_in[6];
    const float* Wr2 = (const float*)d_in[7];
    const float* Wl3 = (const float*)d_in[8];
    const float* b3  = (const float*)d_in[9];
    const float* Wr3 = (const float*)d_in[10];

    int N = in_sizes[0] / 128;
    int E = in_sizes[1] / 2;
    const int* srcp = ei;
    const int* dstp = ei + E;
    size_t P = (size_t)N * 128;            // plane elements

    // ws layout (ushort planes first, then ints, then W images) ~54.8MB
    unsigned short* Xh = (unsigned short*)d_ws;   // x planes, later h2 planes
    unsigned short* Xl = Xh + P;
    unsigned short* Ah = Xl + P;                  // agg planes
    unsigned short* Al = Ah + P;
    int* deg = (int*)(Al + P);
    int* rp  = deg + ((N + 3) & ~3);
    int* cur = rp + ((N + 4) & ~3);
    int* col = cur + ((N + 3) & ~3);
    unsigned short* Wimg = (unsigned short*)(col + ((E + 3) & ~3));  // 3 x 64K ushorts

    // d_out doubles as h1 plane storage, finally holds fp32 output
    unsigned short* Oh = (unsigned short*)d_out;
    unsigned short* Ol = Oh + P;
    float* out = (float*)d_out;

    hipMemsetAsync(deg, 0, (size_t)N * sizeof(int), stream);
    k_hist<<<1024, 256, 0, stream>>>(dstp, deg, E);
    k_scan<<<1, 1024, 0, stream>>>(deg, rp, cur, N);
    k_fill<<<1024, 256, 0, stream>>>(srcp, dstp, cur, col, E);

    k_splitX<<<512, 256, 0, stream>>>(x, Xh, Xl, (int)(P / 4));
    k_splitW<<<128, 256, 0, stream>>>(Wl1, Wr1, Wimg);
    k_splitW<<<128, 256, 0, stream>>>(Wl2, Wr2, Wimg + 65536);
    k_splitW<<<128, 256, 0, stream>>>(Wl3, Wr3, Wimg + 131072);

    int gb = (N + 63) / 64;
    // layer 1: agg(x) -> A; gemm -> h1 planes (d_out)
    k_aggP<<<4096, 256, 0, stream>>>(Xh, Xl, rp, col, Ah, Al, N);
    k_gemm<<<gb, 256, 0, stream>>>(Ah, Al, Xh, Xl, Wimg, b1,
                                   nullptr, Oh, Ol, 1, N);
    // layer 2: agg(h1) -> A; gemm -> h2 planes (ws, x planes now dead)
    k_aggP<<<4096, 256, 0, stream>>>(Oh, Ol, rp, col, Ah, Al, N);
    k_gemm<<<gb, 256, 0, stream>>>(Ah, Al, Oh, Ol, Wimg + 65536, b2,
                                   nullptr, Xh, Xl, 1, N);
    // layer 3: agg(h2) -> A; gemm -> fp32 out (d_out; h planes read from ws)
    k_aggP<<<4096, 256, 0, stream>>>(Xh, Xl, rp, col, Ah, Al, N);
    k_gemm<<<gb, 256, 0, stream>>>(Ah, Al, Xh, Xl, Wimg + 131072, b3,
                                   out, nullptr, nullptr, 0, N);
}

// Round 6
// 487.940 us; speedup vs baseline: 1.1071x; 1.1071x over previous
//
#include <hip/hip_runtime.h>
#include <stdint.h>

// ---------------------------------------------------------------------------
// 3-layer GraphSAGE (mean aggregation) on MI355X — fused agg+GEMM edition.
//
// Per layer, ONE kernel (k_fused): block owns 64 nodes.
//   phase 1: CSR gather-mean of the 64 rows -> fp32 LDS tile (no global agg!)
//   phase 2: out = [agg|h] @ [Wl;Wr] + b via split-bf16 mfma_32x32x16
//            (3-MFMA product ah*bh+ah*bl+al*bh, fp32 accum).
//            A-frags: LDS (agg, split on the fly) / global h planes.
//            B-frags: direct from tiny L2-resident pre-split W image (no LDS).
//   phase 3: epilogue via LDS bounce -> coalesced 16B/lane writes of bf16
//            hi/lo planes (layers 1,2) or fp32 out (layer 3).
// h ping-pong: x(f32,d_in) -> h1 planes(d_out) -> h2 planes(ws) -> f32(d_out).
// No buffer is read and written by the same dispatch.
// ---------------------------------------------------------------------------

using bf16x8 = __attribute__((ext_vector_type(8))) __bf16;
using f32x16 = __attribute__((ext_vector_type(16))) float;

__device__ inline unsigned short f2bf(float v) {           // RNE f32->bf16
    uint32_t u = __float_as_uint(v);
    uint32_t r = u + 0x7FFF + ((u >> 16) & 1);
    return (unsigned short)(r >> 16);
}
__device__ inline float bf2f(unsigned short h) {
    return __uint_as_float(((uint32_t)h) << 16);
}
__device__ inline float uf(uint32_t u) { return __uint_as_float(u); }

__device__ inline void split8(const float* v, bf16x8& h, bf16x8& l) {
    #pragma unroll
    for (int j = 0; j < 8; ++j) {
        unsigned short hs = f2bf(v[j]);
        unsigned short ls = f2bf(v[j] - bf2f(hs));
        ((unsigned short*)&h)[j] = hs;
        ((unsigned short*)&l)[j] = ls;
    }
}

// ---------------- CSR build ----------------
__global__ void k_hist(const int* __restrict__ dst, int* __restrict__ deg, int E)
{
    int i = blockIdx.x * blockDim.x + threadIdx.x;
    int stride = gridDim.x * blockDim.x;
    for (; i < E; i += stride) atomicAdd(&deg[dst[i]], 1);
}

__global__ __launch_bounds__(1024) void k_scan(const int* __restrict__ deg,
                                               int* __restrict__ rp,
                                               int* __restrict__ cur, int n)
{
    __shared__ int wsum[16];
    __shared__ int carry_s;
    int tid = threadIdx.x, lane = tid & 63, w = tid >> 6;
    if (tid == 0) carry_s = 0;
    __syncthreads();
    for (int base = 0; base < n; base += 4096) {
        int i = base + tid * 4;
        int4 v = make_int4(0, 0, 0, 0);
        if (i + 3 < n) v = *(const int4*)(deg + i);
        else {
            if (i     < n) v.x = deg[i];
            if (i + 1 < n) v.y = deg[i + 1];
            if (i + 2 < n) v.z = deg[i + 2];
            if (i + 3 < n) v.w = deg[i + 3];
        }
        int t = v.x + v.y + v.z + v.w;
        int s = t;
        #pragma unroll
        for (int d = 1; d < 64; d <<= 1) { int u = __shfl_up(s, d); if (lane >= d) s += u; }
        if (lane == 63) wsum[w] = s;
        __syncthreads();
        if (w == 0 && lane < 16) {
            int u = wsum[lane];
            #pragma unroll
            for (int d = 1; d < 16; d <<= 1) { int y = __shfl_up(u, d); if (lane >= d) u += y; }
            wsum[lane] = u;
        }
        __syncthreads();
        int carry = carry_s;
        int off = carry + (w ? wsum[w - 1] : 0) + (s - t);
        int r0 = off, r1 = r0 + v.x, r2 = r1 + v.y, r3 = r2 + v.z;
        if (i + 3 < n) {
            *(int4*)(rp + i)  = make_int4(r0, r1, r2, r3);
            *(int4*)(cur + i) = make_int4(r0, r1, r2, r3);
        } else {
            if (i     < n) { rp[i]     = r0; cur[i]     = r0; }
            if (i + 1 < n) { rp[i + 1] = r1; cur[i + 1] = r1; }
            if (i + 2 < n) { rp[i + 2] = r2; cur[i + 2] = r2; }
            if (i + 3 < n) { rp[i + 3] = r3; cur[i + 3] = r3; }
        }
        __syncthreads();
        if (tid == 1023) carry_s = carry + wsum[15];
    }
    __syncthreads();
    if (tid == 0) rp[n] = carry_s;
}

__global__ void k_fill(const int* __restrict__ src, const int* __restrict__ dst,
                       int* __restrict__ cur, int* __restrict__ col, int E)
{
    int i = blockIdx.x * blockDim.x + threadIdx.x;
    int stride = gridDim.x * blockDim.x;
    for (; i < E; i += stride) {
        int p = atomicAdd(&cur[dst[i]], 1);
        col[p] = src[i];
    }
}

// ---------------- W -> pre-split frag-ordered image ----------------
// Virtual W = [Wl;Wr] (256x128). 4 chunks (ch): {Wl,Wr} x {k0..63, k64..127}.
// img[ch*16384 + p*8192 + c*64 + kk] = plane_p( W_sel[(ch&1)*64+kk][c] )
//   (p=0 hi, p=1 lo). A lane's B-frag = 16B at (c*64 + sg*8), L2-resident.
__global__ __launch_bounds__(256) void k_splitW(const float* __restrict__ Wl,
                                                const float* __restrict__ Wr,
                                                unsigned short* __restrict__ img)
{
    int idx = blockIdx.x * 256 + threadIdx.x;       // 32768 total
    int ch  = idx >> 13;
    int rem = idx & 8191;
    int c   = rem >> 6;
    int kk  = rem & 63;
    float v = (ch < 2 ? Wl : Wr)[((ch & 1) * 64 + kk) * 128 + c];
    unsigned short h = f2bf(v);
    unsigned short l = f2bf(v - bf2f(h));
    img[ch * 16384 + rem]        = h;
    img[ch * 16384 + 8192 + rem] = l;
}

// ---------------- fused layer kernel ----------------
// 256 thr = 4 waves (wm=wave>>1 row-half, wn=wave&1 col-half).
// LDS: aggF[64][132] fp32 (33.8KB, +4 pad to stagger banks), reused by epilogue.
template<int INF32, int OUTF32>
__global__ __launch_bounds__(256) void k_fused(const float* __restrict__ xf,
                                               const unsigned short* __restrict__ inH,
                                               const unsigned short* __restrict__ inL,
                                               const int* __restrict__ rp,
                                               const int* __restrict__ col,
                                               const unsigned short* __restrict__ wimg,
                                               const float* __restrict__ bias,
                                               float* __restrict__ outF,
                                               unsigned short* __restrict__ oH,
                                               unsigned short* __restrict__ oL,
                                               int relu, int nNodes)
{
    __shared__ float aggF[64 * 132];
    const int tid  = threadIdx.x;
    const int wave = tid >> 6, l = tid & 63;
    const int lh   = l >> 5, l31 = l & 31;
    const int wm = wave >> 1, wn = wave & 1;
    const int m0w = wm * 32, n0w = wn * 64;
    const int node0 = blockIdx.x * 64;

    // ---- phase 1: gather-mean 16 nodes per wave into LDS fp32 tile ----
    #pragma unroll 1
    for (int j = 0; j < 16; ++j) {
        const int nl = wave * 16 + j;
        const int n  = node0 + nl;
        int s = 0, e = 0;
        if (n < nNodes) { s = rp[n]; e = rp[n + 1]; }
        float a0 = 0.f, a1 = 0.f, b0 = 0.f, b1 = 0.f;
        float c0a = 0.f, c1a = 0.f, d0a = 0.f, d1a = 0.f;
        int i = s;
        if (INF32) {
            for (; i + 4 <= e; i += 4) {
                int e0 = col[i], e1 = col[i+1], e2 = col[i+2], e3 = col[i+3];
                float2 v0 = *(const float2*)(xf + (size_t)e0 * 128 + 2 * l);
                float2 v1 = *(const float2*)(xf + (size_t)e1 * 128 + 2 * l);
                float2 v2 = *(const float2*)(xf + (size_t)e2 * 128 + 2 * l);
                float2 v3 = *(const float2*)(xf + (size_t)e3 * 128 + 2 * l);
                a0 += v0.x; a1 += v0.y; b0 += v1.x; b1 += v1.y;
                c0a += v2.x; c1a += v2.y; d0a += v3.x; d1a += v3.y;
            }
            for (; i < e; ++i) {
                float2 v0 = *(const float2*)(xf + (size_t)col[i] * 128 + 2 * l);
                a0 += v0.x; a1 += v0.y;
            }
        } else {
            for (; i + 4 <= e; i += 4) {
                int e0 = col[i], e1 = col[i+1], e2 = col[i+2], e3 = col[i+3];
                uint32_t h0 = *(const uint32_t*)(inH + (size_t)e0 * 128 + 2 * l);
                uint32_t g0 = *(const uint32_t*)(inL + (size_t)e0 * 128 + 2 * l);
                uint32_t h1 = *(const uint32_t*)(inH + (size_t)e1 * 128 + 2 * l);
                uint32_t g1 = *(const uint32_t*)(inL + (size_t)e1 * 128 + 2 * l);
                uint32_t h2 = *(const uint32_t*)(inH + (size_t)e2 * 128 + 2 * l);
                uint32_t g2 = *(const uint32_t*)(inL + (size_t)e2 * 128 + 2 * l);
                uint32_t h3 = *(const uint32_t*)(inH + (size_t)e3 * 128 + 2 * l);
                uint32_t g3 = *(const uint32_t*)(inL + (size_t)e3 * 128 + 2 * l);
                a0 += uf(h0 << 16) + uf(g0 << 16);
                a1 += uf(h0 & 0xffff0000u) + uf(g0 & 0xffff0000u);
                b0 += uf(h1 << 16) + uf(g1 << 16);
                b1 += uf(h1 & 0xffff0000u) + uf(g1 & 0xffff0000u);
                c0a += uf(h2 << 16) + uf(g2 << 16);
                c1a += uf(h2 & 0xffff0000u) + uf(g2 & 0xffff0000u);
                d0a += uf(h3 << 16) + uf(g3 << 16);
                d1a += uf(h3 & 0xffff0000u) + uf(g3 & 0xffff0000u);
            }
            for (; i < e; ++i) {
                int e0 = col[i];
                uint32_t h0 = *(const uint32_t*)(inH + (size_t)e0 * 128 + 2 * l);
                uint32_t g0 = *(const uint32_t*)(inL + (size_t)e0 * 128 + 2 * l);
                a0 += uf(h0 << 16) + uf(g0 << 16);
                a1 += uf(h0 & 0xffff0000u) + uf(g0 & 0xffff0000u);
            }
        }
        float inv = (e > s) ? (1.f / (float)(e - s)) : 0.f;
        float2 o;
        o.x = ((a0 + b0) + (c0a + d0a)) * inv;
        o.y = ((a1 + b1) + (c1a + d1a)) * inv;
        *(float2*)&aggF[nl * 132 + 2 * l] = o;
    }
    __syncthreads();

    // ---- phase 2: split-bf16 MFMA, no barriers in the loop ----
    f32x16 acc0, acc1;
    #pragma unroll
    for (int i = 0; i < 16; ++i) { acc0[i] = 0.f; acc1[i] = 0.f; }

    const int rowA_loc  = m0w + l31;
    const int rowA_glob = min(node0 + rowA_loc, nNodes - 1);
    const int c0 = n0w + l31, c1 = c0 + 32;

    #pragma unroll
    for (int ch = 0; ch < 4; ++ch) {
        const unsigned short* wb = wimg + ch * 16384;
        #pragma unroll
        for (int ks = 0; ks < 4; ++ks) {
            const int sg   = ks * 2 + lh;
            const int koff = (ch & 1) * 64 + sg * 8;
            bf16x8 a_h, a_l;
            if (ch < 2) {
                float v[8];
                const float* p = &aggF[rowA_loc * 132 + koff];
                *(float4*)v       = *(const float4*)p;
                *(float4*)(v + 4) = *(const float4*)(p + 4);
                split8(v, a_h, a_l);
            } else if (INF32) {
                float v[8];
                const float* p = xf + (size_t)rowA_glob * 128 + koff;
                *(float4*)v       = *(const float4*)p;
                *(float4*)(v + 4) = *(const float4*)(p + 4);
                split8(v, a_h, a_l);
            } else {
                a_h = *(const bf16x8*)(inH + (size_t)rowA_glob * 128 + koff);
                a_l = *(const bf16x8*)(inL + (size_t)rowA_glob * 128 + koff);
            }
            bf16x8 b_h0 = *(const bf16x8*)(wb + c0 * 64 + sg * 8);
            bf16x8 b_l0 = *(const bf16x8*)(wb + 8192 + c0 * 64 + sg * 8);
            bf16x8 b_h1 = *(const bf16x8*)(wb + c1 * 64 + sg * 8);
            bf16x8 b_l1 = *(const bf16x8*)(wb + 8192 + c1 * 64 + sg * 8);
            acc0 = __builtin_amdgcn_mfma_f32_32x32x16_bf16(a_h, b_h0, acc0, 0, 0, 0);
            acc1 = __builtin_amdgcn_mfma_f32_32x32x16_bf16(a_h, b_h1, acc1, 0, 0, 0);
            acc0 = __builtin_amdgcn_mfma_f32_32x32x16_bf16(a_h, b_l0, acc0, 0, 0, 0);
            acc1 = __builtin_amdgcn_mfma_f32_32x32x16_bf16(a_h, b_l1, acc1, 0, 0, 0);
            acc0 = __builtin_amdgcn_mfma_f32_32x32x16_bf16(a_l, b_h0, acc0, 0, 0, 0);
            acc1 = __builtin_amdgcn_mfma_f32_32x32x16_bf16(a_l, b_h1, acc1, 0, 0, 0);
        }
    }

    // ---- phase 3: epilogue via LDS bounce -> coalesced writes ----
    __syncthreads();                    // all aggF frag reads done
    const float bv0 = bias[n0w + l31];
    const float bv1 = bias[n0w + 32 + l31];
    #pragma unroll
    for (int reg = 0; reg < 16; ++reg) {
        int row = (reg & 3) + 8 * (reg >> 2) + 4 * lh;
        int rl  = m0w + row;
        float v0 = acc0[reg] + bv0;
        float v1 = acc1[reg] + bv1;
        if (relu) { v0 = fmaxf(v0, 0.f); v1 = fmaxf(v1, 0.f); }
        aggF[rl * 132 + n0w + l31]      = v0;
        aggF[rl * 132 + n0w + 32 + l31] = v1;
    }
    __syncthreads();
    {
        const int rl = tid >> 2;
        const int gn = node0 + rl;
        if (gn < nNodes) {
            const int cq = (tid & 3) * 32;
            const float* p = &aggF[rl * 132 + cq];
            if (OUTF32) {
                float* o = outF + (size_t)gn * 128 + cq;
                #pragma unroll
                for (int q = 0; q < 8; ++q)
                    *(float4*)(o + q * 4) = *(const float4*)(p + q * 4);
            } else {
                #pragma unroll
                for (int g = 0; g < 4; ++g) {      // 8 cols per group
                    float v[8];
                    *(float4*)v       = *(const float4*)(p + g * 8);
                    *(float4*)(v + 4) = *(const float4*)(p + g * 8 + 4);
                    unsigned short hs[8], ls[8];
                    #pragma unroll
                    for (int q = 0; q < 8; ++q) {
                        hs[q] = f2bf(v[q]);
                        ls[q] = f2bf(v[q] - bf2f(hs[q]));
                    }
                    *(uint4*)(oH + (size_t)gn * 128 + cq + g * 8) = *(uint4*)hs;
                    *(uint4*)(oL + (size_t)gn * 128 + cq + g * 8) = *(uint4*)ls;
                }
            }
        }
    }
}

extern "C" void kernel_launch(void* const* d_in, const int* in_sizes, int n_in,
                              void* d_out, int out_size, void* d_ws, size_t ws_size,
                              hipStream_t stream)
{
    const float* x   = (const float*)d_in[0];
    const int*   ei  = (const int*)d_in[1];
    const float* Wl1 = (const float*)d_in[2];
    const float* b1  = (const float*)d_in[3];
    const float* Wr1 = (const float*)d_in[4];
    const float* Wl2 = (const float*)d_in[5];
    const float* b2  = (const float*)d_in[6];
    const float* Wr2 = (const float*)d_in[7];
    const float* Wl3 = (const float*)d_in[8];
    const float* b3  = (const float*)d_in[9];
    const float* Wr3 = (const float*)d_in[10];

    int N = in_sizes[0] / 128;
    int E = in_sizes[1] / 2;
    const int* srcp = ei;
    const int* dstp = ei + E;
    size_t P = (size_t)N * 128;            // plane elements

    // ws layout: h2 planes + CSR ints + 3 W images  (~29 MB)
    unsigned short* Hh = (unsigned short*)d_ws;     // h2 hi plane
    unsigned short* Hl = Hh + P;                    // h2 lo plane
    int* deg = (int*)(Hl + P);
    int* rp  = deg + ((N + 3) & ~3);
    int* cur = rp + ((N + 4) & ~3);
    int* col = cur + ((N + 3) & ~3);
    unsigned short* Wimg = (unsigned short*)(col + ((E + 3) & ~3));  // 3 x 65536

    // d_out: h1 planes for layers 1-2, final fp32 output for layer 3
    unsigned short* Oh = (unsigned short*)d_out;
    unsigned short* Ol = Oh + P;
    float* out = (float*)d_out;

    hipMemsetAsync(deg, 0, (size_t)N * sizeof(int), stream);
    k_hist<<<1024, 256, 0, stream>>>(dstp, deg, E);
    k_scan<<<1, 1024, 0, stream>>>(deg, rp, cur, N);
    k_fill<<<1024, 256, 0, stream>>>(srcp, dstp, cur, col, E);

    k_splitW<<<128, 256, 0, stream>>>(Wl1, Wr1, Wimg);
    k_splitW<<<128, 256, 0, stream>>>(Wl2, Wr2, Wimg + 65536);
    k_splitW<<<128, 256, 0, stream>>>(Wl3, Wr3, Wimg + 131072);

    int gb = (N + 63) / 64;
    // layer 1: reads x (f32), writes h1 planes (d_out)
    k_fused<1, 0><<<gb, 256, 0, stream>>>(x, nullptr, nullptr, rp, col,
                                          Wimg, b1, nullptr, Oh, Ol, 1, N);
    // layer 2: reads h1 planes (d_out), writes h2 planes (ws)
    k_fused<0, 0><<<gb, 256, 0, stream>>>(nullptr, Oh, Ol, rp, col,
                                          Wimg + 65536, b2, nullptr, Hh, Hl, 1, N);
    // layer 3: reads h2 planes (ws), writes fp32 out (d_out)
    k_fused<0, 1><<<gb, 256, 0, stream>>>(nullptr, Hh, Hl, rp, col,
                                          Wimg + 131072, b3, out, nullptr, nullptr, 0, N);
}